// Round 1
// baseline (351.808 us; speedup 1.0000x reference)
//
#include <hip/hip_runtime.h>
#include <hip/hip_bf16.h>

typedef __attribute__((ext_vector_type(8))) short short8;
typedef __attribute__((ext_vector_type(4))) float f32x4;

__device__ inline short bf16r(float f) {
    union { float f; unsigned u; } v; v.f = f;
    unsigned r = v.u + 0x7FFFu + ((v.u >> 16) & 1u);
    return (short)(r >> 16);
}

// ---------------- elementwise cast fp32 -> bf16 ----------------
__global__ void castk(const float* __restrict__ in, short* __restrict__ out, int n4) {
    int i = blockIdx.x * 256 + threadIdx.x;
    if (i < n4) {
        float4 v = ((const float4*)in)[i];
        short4 o;
        o.x = bf16r(v.x); o.y = bf16r(v.y); o.z = bf16r(v.z); o.w = bf16r(v.w);
        ((short4*)out)[i] = o;
    }
}

// ---------------- transpose-cast fp32[R][C] -> bf16[C][R] ----------------
__global__ void tcast(const float* __restrict__ src, short* __restrict__ dst, int R, int C) {
    __shared__ float tile[32][33];
    int bi = blockIdx.x, bj = blockIdx.y;           // bi over R/32, bj over C/32
    int tx = threadIdx.x & 31, ty = threadIdx.x >> 5;
#pragma unroll
    for (int p = 0; p < 4; p++)
        tile[ty + p * 8][tx] = src[(long)(bi * 32 + ty + p * 8) * C + bj * 32 + tx];
    __syncthreads();
#pragma unroll
    for (int p = 0; p < 4; p++)
        dst[(long)(bj * 32 + ty + p * 8) * R + bi * 32 + tx] = bf16r(tile[tx][ty + p * 8]);
}

// ---------------- transpose V slice of qkv (bf16) -> Vt[a][r=h*64+d][k] ----------------
__global__ void vtrans(const short* __restrict__ qkv, short* __restrict__ Vt) {
    __shared__ short tile[32][33];
    int a = blockIdx.z, bi = blockIdx.x, bj = blockIdx.y;  // bi: k-tile, bj: r-tile
    int tx = threadIdx.x & 31, ty = threadIdx.x >> 5;
#pragma unroll
    for (int p = 0; p < 4; p++) {
        int k = bi * 32 + ty + p * 8;
        int r = bj * 32 + tx;
        tile[ty + p * 8][tx] = qkv[(long)(a * 1024 + k) * 3072 + 2048 + r];
    }
    __syncthreads();
#pragma unroll
    for (int p = 0; p < 4; p++) {
        int r = bj * 32 + ty + p * 8;
        int k = bi * 32 + tx;
        Vt[(long)a * 1048576 + (long)r * 1024 + k] = tile[tx][ty + p * 8];
    }
}

// ---------------- bf16 GEMM: C[M][N] = A[M][K] * Bt[N][K]^T (+bias) ----------------
template<int OUT_BF16>
__global__ __launch_bounds__(256, 2)
void gemm_bt(const short* __restrict__ A, const short* __restrict__ Bt,
             void* __restrict__ Cout, const float* __restrict__ bias,
             int M, int N, int K) {
    __shared__ short As[2][128 * 32];
    __shared__ short Bs[2][128 * 32];
    const int tid = threadIdx.x, w = tid >> 6, lane = tid & 63;
    const int wr = w >> 1, wc = w & 1;
    const int l15 = lane & 15, lhi = lane >> 4;
    const int m0 = blockIdx.y * 128, n0 = blockIdx.x * 128;
    f32x4 acc[4][4] = {};
    const int NT = K / 32;

    auto stage = [&](int buf, int t) {
        int k0 = t * 32;
#pragma unroll
        for (int j = 0; j < 2; j++) {
            int chunk = w * 128 + j * 64 + lane;
            int row = chunk >> 2, cc = chunk & 3;
            short8 va = *(const short8*)(A + (long)(m0 + row) * K + k0 + cc * 8);
            *(short8*)(&As[buf][chunk * 8]) = va;
            short8 vb = *(const short8*)(Bt + (long)(n0 + row) * K + k0 + cc * 8);
            *(short8*)(&Bs[buf][chunk * 8]) = vb;
        }
    };

    stage(0, 0);
    __syncthreads();
    int buf = 0;
    for (int t = 0; t < NT; t++) {
        if (t + 1 < NT) stage(buf ^ 1, t + 1);
        short8 af[4], bfr[4];
#pragma unroll
        for (int i = 0; i < 4; i++) {
            af[i]  = *(const short8*)(&As[buf][(wr * 64 + i * 16 + l15) * 32 + lhi * 8]);
            bfr[i] = *(const short8*)(&Bs[buf][(wc * 64 + i * 16 + l15) * 32 + lhi * 8]);
        }
#pragma unroll
        for (int i = 0; i < 4; i++)
#pragma unroll
            for (int j = 0; j < 4; j++)
                acc[i][j] = __builtin_amdgcn_mfma_f32_16x16x32_bf16(af[i], bfr[j], acc[i][j], 0, 0, 0);
        __syncthreads();
        buf ^= 1;
    }
#pragma unroll
    for (int i = 0; i < 4; i++)
#pragma unroll
        for (int j = 0; j < 4; j++)
#pragma unroll
            for (int r = 0; r < 4; r++) {
                int row = m0 + wr * 64 + i * 16 + lhi * 4 + r;
                int col = n0 + wc * 64 + j * 16 + l15;
                float v = acc[i][j][r];
                if (OUT_BF16) ((short*)Cout)[(long)row * N + col] = bf16r(v);
                else          ((float*)Cout)[(long)row * N + col] = v + bias[col];
            }
}

// ---------------- fused attention with softmax over HEADS axis ----------------
// grid (32 qtiles, 8 batches), 512 threads = 8 waves = 2 q-subtiles x 4 head-groups
#define SCALE 0.03125f

__global__ __launch_bounds__(512, 2)
void attn_kernel(const short* __restrict__ qkv, const short* __restrict__ Vt,
                 short* __restrict__ ctx) {
    __shared__ short vbuf[1024 * 32];              // 64KB: [r=h*64+d][k 0..31], 16B-chunk XOR swizzle
    __shared__ float red[2][2][4][2][4][64];       // 32KB: [half][wr][hg][kt16][reg][lane]
    __shared__ short pbuf[8][4][16][40];           // 40KB: per-wave P tiles, padded k-stride

    const int tid = threadIdx.x, w = tid >> 6, lane = tid & 63;
    const int wr = w >> 2, hg = w & 3;
    const int a = blockIdx.y, qt = blockIdx.x;
    const int q0 = qt * 32;
    const int l15 = lane & 15, lhi = lane >> 4;
    const int qrow = a * 1024 + q0 + wr * 16 + l15;

    // preload Q fragments: A[m=q][kk=d], per head 2 chunks of 32 d
    short8 qf[4][2];
#pragma unroll
    for (int hl = 0; hl < 4; hl++) {
        int H = hg * 4 + hl;
#pragma unroll
        for (int df = 0; df < 2; df++)
            qf[hl][df] = *(const short8*)(qkv + (long)qrow * 3072 + H * 64 + df * 32 + lhi * 8);
    }

    f32x4 oacc[4][4] = {};
    const short* Vta = Vt + (long)a * 1048576;

    for (int kt = 0; kt < 32; kt++) {
        int k0 = kt * 32;
        __syncthreads();                           // bar0: prev PV reads done before vbuf overwrite
        // stage V tile: vbuf[r][c-chunk swizzled] <- Vt[a][r][k0 + c*8]
#pragma unroll
        for (int j = 0; j < 8; j++) {
            int ci = w * 512 + j * 64 + lane;
            int r = ci >> 2, c = ci & 3;
            short8 v = *(const short8*)(Vta + r * 1024 + k0 + c * 8);
            *(short8*)(&vbuf[r * 32 + ((c ^ (r & 3)) * 8)]) = v;
        }
        // QK^T: S[q,k] for this wave's 4 heads
        f32x4 sacc[4][2] = {};
#pragma unroll
        for (int hl = 0; hl < 4; hl++) {
            int H = hg * 4 + hl;
#pragma unroll
            for (int kt16 = 0; kt16 < 2; kt16++) {
                int krow = a * 1024 + k0 + kt16 * 16 + l15;
#pragma unroll
                for (int df = 0; df < 2; df++) {
                    short8 kf = *(const short8*)(qkv + (long)krow * 3072 + 1024 + H * 64 + df * 32 + lhi * 8);
                    sacc[hl][kt16] = __builtin_amdgcn_mfma_f32_16x16x32_bf16(qf[hl][df], kf, sacc[hl][kt16], 0, 0, 0);
                }
            }
        }
        // softmax over the 16 heads at each (q,k): local(4 heads) then cross-wave(4 waves)
#pragma unroll
        for (int kt16 = 0; kt16 < 2; kt16++)
#pragma unroll
            for (int r = 0; r < 4; r++) {
                float m = sacc[0][kt16][r];
#pragma unroll
                for (int hl = 1; hl < 4; hl++) m = fmaxf(m, sacc[hl][kt16][r]);
                red[0][wr][hg][kt16][r][lane] = m * SCALE;
            }
        __syncthreads();                           // bar1
        float gmax[2][4];
#pragma unroll
        for (int kt16 = 0; kt16 < 2; kt16++)
#pragma unroll
            for (int r = 0; r < 4; r++) {
                float m = red[0][wr][0][kt16][r][lane];
#pragma unroll
                for (int g = 1; g < 4; g++) m = fmaxf(m, red[0][wr][g][kt16][r][lane]);
                gmax[kt16][r] = m;
            }
        float lsum[2][4] = {};
#pragma unroll
        for (int hl = 0; hl < 4; hl++)
#pragma unroll
            for (int kt16 = 0; kt16 < 2; kt16++)
#pragma unroll
                for (int r = 0; r < 4; r++) {
                    float e = __expf(sacc[hl][kt16][r] * SCALE - gmax[kt16][r]);
                    sacc[hl][kt16][r] = e;
                    lsum[kt16][r] += e;
                }
#pragma unroll
        for (int kt16 = 0; kt16 < 2; kt16++)
#pragma unroll
            for (int r = 0; r < 4; r++)
                red[1][wr][hg][kt16][r][lane] = lsum[kt16][r];
        __syncthreads();                           // bar2
#pragma unroll
        for (int kt16 = 0; kt16 < 2; kt16++)
#pragma unroll
            for (int r = 0; r < 4; r++) {
                float s = red[1][wr][0][kt16][r][lane];
#pragma unroll
                for (int g = 1; g < 4; g++) s += red[1][wr][g][kt16][r][lane];
                float rinv = 1.0f / s;
#pragma unroll
                for (int hl = 0; hl < 4; hl++)
                    pbuf[w][hl][lhi * 4 + r][kt16 * 16 + l15] = bf16r(sacc[hl][kt16][r] * rinv);
            }
        __syncthreads();                           // bar3: vbuf staged + pbuf visible
        // PV: oacc[q,d] += P[q,k] * V[k,d]
#pragma unroll
        for (int hl = 0; hl < 4; hl++) {
            int H = hg * 4 + hl;
            short8 pf = *(const short8*)(&pbuf[w][hl][l15][lhi * 8]);
#pragma unroll
            for (int db = 0; db < 4; db++) {
                int r = H * 64 + db * 16 + l15;
                short8 vf = *(const short8*)(&vbuf[r * 32 + ((lhi ^ (r & 3)) * 8)]);
                oacc[hl][db] = __builtin_amdgcn_mfma_f32_16x16x32_bf16(pf, vf, oacc[hl][db], 0, 0, 0);
            }
        }
    }
    // epilogue: ctx[a*1024 + q][h*64 + d] (bf16)
#pragma unroll
    for (int hl = 0; hl < 4; hl++) {
        int H = hg * 4 + hl;
#pragma unroll
        for (int db = 0; db < 4; db++)
#pragma unroll
            for (int r = 0; r < 4; r++) {
                int qq = q0 + wr * 16 + lhi * 4 + r;
                int col = H * 64 + db * 16 + l15;
                ctx[(long)(a * 1024 + qq) * 1024 + col] = bf16r(oacc[hl][db][r]);
            }
    }
}

extern "C" void kernel_launch(void* const* d_in, const int* in_sizes, int n_in,
                              void* d_out, int out_size, void* d_ws, size_t ws_size,
                              hipStream_t stream) {
    const float* x     = (const float*)d_in[0];
    const float* w_qkv = (const float*)d_in[1];
    const float* w_out = (const float*)d_in[2];
    const float* b_out = (const float*)d_in[3];
    float* out = (float*)d_out;

    char* ws = (char*)d_ws;
    short* xb    = (short*)(ws);               // 16,777,216 B  x in bf16
    short* wqkvT = (short*)(ws + 16777216);    //  6,291,456 B  w_qkv^T bf16 [3072][1024]
    short* woT   = (short*)(ws + 23068672);    //  2,097,152 B  w_out^T bf16 [1024][1024]
    short* qkv   = (short*)(ws + 25165824);    // 50,331,648 B  qkv bf16 [8192][3072]
    short* Vt    = (short*)(ws + 75497472);    // 16,777,216 B  V^T bf16 [8][1024][1024]
    short* ctx   = (short*)(ws + 92274688);    // 16,777,216 B  attn out bf16 [8192][1024]
    if (ws_size < 109051904u) return;          // need 109 MB scratch

    castk<<<8192, 256, 0, stream>>>(x, xb, 2097152);
    tcast<<<dim3(32, 96), 256, 0, stream>>>(w_qkv, wqkvT, 1024, 3072);
    tcast<<<dim3(32, 32), 256, 0, stream>>>(w_out, woT, 1024, 1024);
    gemm_bt<1><<<dim3(24, 64), 256, 0, stream>>>(xb, wqkvT, (void*)qkv, nullptr, 8192, 3072, 1024);
    vtrans<<<dim3(32, 32, 8), 256, 0, stream>>>(qkv, Vt);
    attn_kernel<<<dim3(32, 8), 512, 0, stream>>>(qkv, Vt, ctx);
    gemm_bt<0><<<dim3(8, 64), 256, 0, stream>>>(ctx, woT, (void*)out, b_out, 8192, 1024, 1024);
}

// Round 2
// 254.786 us; speedup vs baseline: 1.3808x; 1.3808x over previous
//
#include <hip/hip_runtime.h>
#include <hip/hip_bf16.h>

typedef __attribute__((ext_vector_type(8))) short short8;
typedef __attribute__((ext_vector_type(4))) float f32x4;

#define SC_LOG2E 0.04508422f   // (1/32) * log2(e)

__device__ inline short bf16r(float f) {
    union { float f; unsigned u; } v; v.f = f;
    unsigned r = v.u + 0x7FFFu + ((v.u >> 16) & 1u);
    return (short)(r >> 16);
}
__device__ inline float bf2f(unsigned short u) {
    union { unsigned u; float f; } v; v.u = ((unsigned)u) << 16;
    return v.f;
}

#define GLOAD_LDS16(gp, lp) __builtin_amdgcn_global_load_lds( \
    (const __attribute__((address_space(1))) unsigned int*)(gp), \
    (__attribute__((address_space(3))) unsigned int*)(lp), 16, 0, 0)

// ---------------- elementwise cast fp32 -> bf16 ----------------
__global__ void castk(const float* __restrict__ in, short* __restrict__ out, int n4) {
    int i = blockIdx.x * 256 + threadIdx.x;
    if (i < n4) {
        float4 v = ((const float4*)in)[i];
        short4 o;
        o.x = bf16r(v.x); o.y = bf16r(v.y); o.z = bf16r(v.z); o.w = bf16r(v.w);
        ((short4*)out)[i] = o;
    }
}

// ---------------- transpose-cast fp32[R][C] -> bf16[C][R] ----------------
__global__ void tcast(const float* __restrict__ src, short* __restrict__ dst, int R, int C) {
    __shared__ float tile[32][33];
    int bi = blockIdx.x, bj = blockIdx.y;
    int tx = threadIdx.x & 31, ty = threadIdx.x >> 5;
#pragma unroll
    for (int p = 0; p < 4; p++)
        tile[ty + p * 8][tx] = src[(long)(bi * 32 + ty + p * 8) * C + bj * 32 + tx];
    __syncthreads();
#pragma unroll
    for (int p = 0; p < 4; p++)
        dst[(long)(bj * 32 + ty + p * 8) * R + bi * 32 + tx] = bf16r(tile[tx][ty + p * 8]);
}

// ---------------- transpose V slice of qkv (bf16) -> Vt[a][r=h*64+d][k] ----------------
__global__ void vtrans(const short* __restrict__ qkv, short* __restrict__ Vt) {
    __shared__ short tile[32][33];
    int a = blockIdx.z, bi = blockIdx.x, bj = blockIdx.y;
    int tx = threadIdx.x & 31, ty = threadIdx.x >> 5;
#pragma unroll
    for (int p = 0; p < 4; p++) {
        int k = bi * 32 + ty + p * 8;
        int r = bj * 32 + tx;
        tile[ty + p * 8][tx] = qkv[(long)(a * 1024 + k) * 3072 + 2048 + r];
    }
    __syncthreads();
#pragma unroll
    for (int p = 0; p < 4; p++) {
        int r = bj * 32 + ty + p * 8;
        int k = bi * 32 + tx;
        Vt[(long)a * 1048576 + (long)r * 1024 + k] = tile[tx][ty + p * 8];
    }
}

// ---------------- bf16 GEMM: C[M][N] = A[M][K] * Bt[N][K]^T (+bias) ----------------
template<int OUT_BF16>
__global__ __launch_bounds__(256, 2)
void gemm_bt(const short* __restrict__ A, const short* __restrict__ Bt,
             void* __restrict__ Cout, const float* __restrict__ bias,
             int M, int N, int K) {
    __shared__ short As[2][128 * 32];
    __shared__ short Bs[2][128 * 32];
    const int tid = threadIdx.x, w = tid >> 6, lane = tid & 63;
    const int wr = w >> 1, wc = w & 1;
    const int l15 = lane & 15, lhi = lane >> 4;
    const int m0 = blockIdx.y * 128, n0 = blockIdx.x * 128;
    f32x4 acc[4][4] = {};
    const int NT = K / 32;

    auto stage = [&](int buf, int t) {
        int k0 = t * 32;
#pragma unroll
        for (int j = 0; j < 2; j++) {
            int chunk = w * 128 + j * 64 + lane;
            int row = chunk >> 2, cc = chunk & 3;
            GLOAD_LDS16(A  + (long)(m0 + row) * K + k0 + cc * 8, &As[buf][chunk * 8]);
            GLOAD_LDS16(Bt + (long)(n0 + row) * K + k0 + cc * 8, &Bs[buf][chunk * 8]);
        }
    };

    stage(0, 0);
    __syncthreads();
    int buf = 0;
    for (int t = 0; t < NT; t++) {
        if (t + 1 < NT) stage(buf ^ 1, t + 1);
        short8 af[4], bfr[4];
#pragma unroll
        for (int i = 0; i < 4; i++) {
            af[i]  = *(const short8*)(&As[buf][(wr * 64 + i * 16 + l15) * 32 + lhi * 8]);
            bfr[i] = *(const short8*)(&Bs[buf][(wc * 64 + i * 16 + l15) * 32 + lhi * 8]);
        }
#pragma unroll
        for (int i = 0; i < 4; i++)
#pragma unroll
            for (int j = 0; j < 4; j++)
                acc[i][j] = __builtin_amdgcn_mfma_f32_16x16x32_bf16(af[i], bfr[j], acc[i][j], 0, 0, 0);
        __syncthreads();
        buf ^= 1;
    }
#pragma unroll
    for (int i = 0; i < 4; i++)
#pragma unroll
        for (int j = 0; j < 4; j++)
#pragma unroll
            for (int r = 0; r < 4; r++) {
                int row = m0 + wr * 64 + i * 16 + lhi * 4 + r;
                int col = n0 + wc * 64 + j * 16 + l15;
                float v = acc[i][j][r];
                if (OUT_BF16) ((short*)Cout)[(long)row * N + col] = bf16r(v);
                else          ((float*)Cout)[(long)row * N + col] = v + bias[col];
            }
}

// ---------------- Phase A: Dinv[a][q][k] = 1 / sum_h exp2(S_h * c) ----------------
// grid (8 ktiles, 8 qtiles, 8 a), 256 thr = 4 waves (2x2), tile 128q x 128k
__global__ __launch_bounds__(256, 2)
void dsum_kernel(const short* __restrict__ qkv, short* __restrict__ Dinv) {
    __shared__ short Qs[2][128 * 64];
    __shared__ short Ks[2][128 * 64];
    const int tid = threadIdx.x, w = tid >> 6, lane = tid & 63;
    const int wr = w >> 1, wc = w & 1;
    const int l15 = lane & 15, lhi = lane >> 4;
    const int a = blockIdx.z, q0 = blockIdx.y * 128, k0 = blockIdx.x * 128;
    const long qb = (long)a * 1024 * 3072;
    f32x4 dacc[4][4] = {};

    auto stage = [&](int buf, int h) {
#pragma unroll
        for (int j = 0; j < 4; j++) {
            int c = (w * 4 + j) * 64 + lane;          // 1024 16B chunks per matrix
            int row = c >> 3, cc = (c & 7) ^ (row & 7); // pre-swizzled source (T2, rule #21)
            GLOAD_LDS16(qkv + qb + (long)(q0 + row) * 3072 + h * 64 + cc * 8,        &Qs[buf][c * 8]);
            GLOAD_LDS16(qkv + qb + (long)(k0 + row) * 3072 + 1024 + h * 64 + cc * 8, &Ks[buf][c * 8]);
        }
    };

    stage(0, 0);
    __syncthreads();
    int buf = 0;
    for (int h = 0; h < 16; h++) {
        if (h < 15) stage(buf ^ 1, h + 1);
        short8 af[4][2], bfv[4][2];
#pragma unroll
        for (int i = 0; i < 4; i++) {
            int row = wr * 64 + i * 16 + l15;
#pragma unroll
            for (int df = 0; df < 2; df++)
                af[i][df] = *(const short8*)(&Qs[buf][row * 64 + (((df * 4 + lhi) ^ (row & 7)) * 8)]);
        }
#pragma unroll
        for (int j = 0; j < 4; j++) {
            int row = wc * 64 + j * 16 + l15;
#pragma unroll
            for (int df = 0; df < 2; df++)
                bfv[j][df] = *(const short8*)(&Ks[buf][row * 64 + (((df * 4 + lhi) ^ (row & 7)) * 8)]);
        }
#pragma unroll
        for (int i = 0; i < 4; i++)
#pragma unroll
            for (int j = 0; j < 4; j++) {
                f32x4 s = {};
                s = __builtin_amdgcn_mfma_f32_16x16x32_bf16(af[i][0], bfv[j][0], s, 0, 0, 0);
                s = __builtin_amdgcn_mfma_f32_16x16x32_bf16(af[i][1], bfv[j][1], s, 0, 0, 0);
#pragma unroll
                for (int r = 0; r < 4; r++)
                    dacc[i][j][r] += exp2f(s[r] * SC_LOG2E);
            }
        __syncthreads();
        buf ^= 1;
    }
#pragma unroll
    for (int i = 0; i < 4; i++)
#pragma unroll
        for (int j = 0; j < 4; j++)
#pragma unroll
            for (int r = 0; r < 4; r++) {
                int q = q0 + wr * 64 + i * 16 + lhi * 4 + r;
                int k = k0 + wc * 64 + j * 16 + l15;
                Dinv[((long)a * 1024 + q) * 1024 + k] = bf16r(1.0f / dacc[i][j][r]);
            }
}

// ---------------- Phase B: per-(a,h) attention with precomputed normalizer ----------------
// grid (8 qtiles, 16 h, 8 a), 256 thr = 4 waves; wave owns 32 q x 64 d, loops k in tiles of 64
__global__ __launch_bounds__(256, 2)
void attn2_kernel(const short* __restrict__ qkv, const short* __restrict__ Vt,
                  const short* __restrict__ Dinv, short* __restrict__ ctx) {
    __shared__ short Ks[2][64 * 64];
    __shared__ short Vs[2][64 * 64];
    __shared__ short pb[4][32 * 64];
    const int tid = threadIdx.x, w = tid >> 6, lane = tid & 63;
    const int l15 = lane & 15, lhi = lane >> 4;
    const int a = blockIdx.z, h = blockIdx.y, q0 = blockIdx.x * 128;
    const int qw = q0 + w * 32;
    const long qb = (long)a * 1024 * 3072;
    const long db = (long)a * 1024 * 1024;

    short8 qf[2][2];
#pragma unroll
    for (int qi = 0; qi < 2; qi++)
#pragma unroll
        for (int df = 0; df < 2; df++)
            qf[qi][df] = *(const short8*)(qkv + qb + (long)(qw + qi * 16 + l15) * 3072 + h * 64 + df * 32 + lhi * 8);

    f32x4 oacc[2][4] = {};

    auto stage = [&](int buf, int t) {
        int k0 = t * 64;
#pragma unroll
        for (int j = 0; j < 2; j++) {
            int c = (w * 2 + j) * 64 + lane;            // 512 chunks each
            int row = c >> 3, cc = (c & 7) ^ (row & 7);
            GLOAD_LDS16(qkv + qb + (long)(k0 + row) * 3072 + 1024 + h * 64 + cc * 8, &Ks[buf][c * 8]);
            GLOAD_LDS16(Vt + (long)a * 1048576 + (long)(h * 64 + row) * 1024 + k0 + cc * 8, &Vs[buf][c * 8]);
        }
    };

    stage(0, 0);
    __syncthreads();
    int buf = 0;
    for (int t = 0; t < 16; t++) {
        int k0 = t * 64;
        // Dinv prefetch (issued before stage so stage's vmcnt stays younger)
        unsigned short dv[2][4][4];
#pragma unroll
        for (int qi = 0; qi < 2; qi++)
#pragma unroll
            for (int kj = 0; kj < 4; kj++)
#pragma unroll
                for (int r = 0; r < 4; r++)
                    dv[qi][kj][r] = ((const unsigned short*)Dinv)[db + (long)(qw + qi * 16 + lhi * 4 + r) * 1024 + k0 + kj * 16 + l15];
        if (t < 15) stage(buf ^ 1, t + 1);
        // QK^T: sacc[qi][kj] over K=64
        f32x4 sacc[2][4] = {};
#pragma unroll
        for (int kj = 0; kj < 4; kj++) {
            int row = kj * 16 + l15;
#pragma unroll
            for (int df = 0; df < 2; df++) {
                short8 kf = *(const short8*)(&Ks[buf][row * 64 + (((df * 4 + lhi) ^ (row & 7)) * 8)]);
#pragma unroll
                for (int qi = 0; qi < 2; qi++)
                    sacc[qi][kj] = __builtin_amdgcn_mfma_f32_16x16x32_bf16(qf[qi][df], kf, sacc[qi][kj], 0, 0, 0);
            }
        }
        // P = exp2(s*c) * Dinv -> per-wave LDS (swizzled), same-wave only (no barrier)
#pragma unroll
        for (int qi = 0; qi < 2; qi++)
#pragma unroll
            for (int kj = 0; kj < 4; kj++)
#pragma unroll
                for (int r = 0; r < 4; r++) {
                    float p = exp2f(sacc[qi][kj][r] * SC_LOG2E) * bf2f(dv[qi][kj][r]);
                    int row = qi * 16 + lhi * 4 + r, col = kj * 16 + l15;
                    pb[w][row * 64 + (((col >> 3) ^ (row & 7)) * 8) + (col & 7)] = bf16r(p);
                }
        // PV: oacc[qi][dj] += P[q,k] * Vt[d,k]
#pragma unroll
        for (int qi = 0; qi < 2; qi++) {
            int prow = qi * 16 + l15;
            short8 pf[2];
#pragma unroll
            for (int kc = 0; kc < 2; kc++)
                pf[kc] = *(const short8*)(&pb[w][prow * 64 + (((kc * 4 + lhi) ^ (prow & 7)) * 8)]);
#pragma unroll
            for (int dj = 0; dj < 4; dj++) {
                int vrow = dj * 16 + l15;
#pragma unroll
                for (int kc = 0; kc < 2; kc++) {
                    short8 vf = *(const short8*)(&Vs[buf][vrow * 64 + (((kc * 4 + lhi) ^ (vrow & 7)) * 8)]);
                    oacc[qi][dj] = __builtin_amdgcn_mfma_f32_16x16x32_bf16(pf[kc], vf, oacc[qi][dj], 0, 0, 0);
                }
            }
        }
        __syncthreads();
        buf ^= 1;
    }
#pragma unroll
    for (int qi = 0; qi < 2; qi++)
#pragma unroll
        for (int dj = 0; dj < 4; dj++)
#pragma unroll
            for (int r = 0; r < 4; r++) {
                int q = qw + qi * 16 + lhi * 4 + r;
                ctx[((long)a * 1024 + q) * 1024 + h * 64 + dj * 16 + l15] = bf16r(oacc[qi][dj][r]);
            }
}

extern "C" void kernel_launch(void* const* d_in, const int* in_sizes, int n_in,
                              void* d_out, int out_size, void* d_ws, size_t ws_size,
                              hipStream_t stream) {
    const float* x     = (const float*)d_in[0];
    const float* w_qkv = (const float*)d_in[1];
    const float* w_out = (const float*)d_in[2];
    const float* b_out = (const float*)d_in[3];
    float* out = (float*)d_out;

    char* ws = (char*)d_ws;
    short* xb    = (short*)(ws);               // 16 MB  x bf16 (dead after gemm1)
    short* Dinv  = (short*)(ws);               // 16 MB  Dinv bf16 (reuses xb slot)
    short* wqkvT = (short*)(ws + 16777216);    //  6 MB  w_qkv^T bf16 [3072][1024]
    short* woT   = (short*)(ws + 23068672);    //  2 MB  w_out^T bf16 [1024][1024]
    short* qkv   = (short*)(ws + 25165824);    // 48 MB  qkv bf16 [8192][3072]
    short* Vt    = (short*)(ws + 75497472);    // 16 MB  V^T bf16 [8][1024][1024]
    short* ctx   = (short*)(ws + 92274688);    // 16 MB  attn out bf16 [8192][1024]
    if (ws_size < 109051904u) return;

    castk<<<8192, 256, 0, stream>>>(x, xb, 2097152);
    tcast<<<dim3(32, 96), 256, 0, stream>>>(w_qkv, wqkvT, 1024, 3072);
    tcast<<<dim3(32, 32), 256, 0, stream>>>(w_out, woT, 1024, 1024);
    gemm_bt<1><<<dim3(24, 64), 256, 0, stream>>>(xb, wqkvT, (void*)qkv, nullptr, 8192, 3072, 1024);
    vtrans<<<dim3(32, 32, 8), 256, 0, stream>>>(qkv, Vt);
    dsum_kernel<<<dim3(8, 8, 8), 256, 0, stream>>>(qkv, Dinv);
    attn2_kernel<<<dim3(8, 16, 8), 256, 0, stream>>>(qkv, Vt, Dinv, ctx);
    gemm_bt<0><<<dim3(8, 64), 256, 0, stream>>>(ctx, woT, (void*)out, b_out, 8192, 1024, 1024);
}

// Round 3
// 236.702 us; speedup vs baseline: 1.4863x; 1.0764x over previous
//
#include <hip/hip_runtime.h>
#include <hip/hip_bf16.h>

typedef __attribute__((ext_vector_type(8))) short short8;
typedef __attribute__((ext_vector_type(4))) short short4v;
typedef __attribute__((ext_vector_type(4))) float f32x4;

#define SC_LOG2E 0.04508422f   // (1/32) * log2(e)

__device__ inline short bf16r(float f) {
    union { float f; unsigned u; } v; v.f = f;
    unsigned r = v.u + 0x7FFFu + ((v.u >> 16) & 1u);
    return (short)(r >> 16);
}
__device__ inline float bf2f(unsigned short u) {
    union { unsigned u; float f; } v; v.u = ((unsigned)u) << 16;
    return v.f;
}

#define GLOAD_LDS16(gp, lp) __builtin_amdgcn_global_load_lds( \
    (const __attribute__((address_space(1))) unsigned int*)(gp), \
    (__attribute__((address_space(3))) unsigned int*)(lp), 16, 0, 0)

// ---------------- elementwise cast fp32 -> bf16 ----------------
__global__ void castk(const float* __restrict__ in, short* __restrict__ out, int n4) {
    int i = blockIdx.x * 256 + threadIdx.x;
    if (i < n4) {
        float4 v = ((const float4*)in)[i];
        short4 o;
        o.x = bf16r(v.x); o.y = bf16r(v.y); o.z = bf16r(v.z); o.w = bf16r(v.w);
        ((short4*)out)[i] = o;
    }
}

// ---------------- transpose-cast fp32[R][C] -> bf16[C][R] ----------------
__global__ void tcast(const float* __restrict__ src, short* __restrict__ dst, int R, int C) {
    __shared__ float tile[32][33];
    int bi = blockIdx.x, bj = blockIdx.y;
    int tx = threadIdx.x & 31, ty = threadIdx.x >> 5;
#pragma unroll
    for (int p = 0; p < 4; p++)
        tile[ty + p * 8][tx] = src[(long)(bi * 32 + ty + p * 8) * C + bj * 32 + tx];
    __syncthreads();
#pragma unroll
    for (int p = 0; p < 4; p++)
        dst[(long)(bj * 32 + ty + p * 8) * R + bi * 32 + tx] = bf16r(tile[tx][ty + p * 8]);
}

// ---------------- transpose V slice of qkv (bf16) -> Vt[a][r=h*64+d][k] ----------------
__global__ void vtrans(const short* __restrict__ qkv, short* __restrict__ Vt) {
    __shared__ short tile[32][33];
    int a = blockIdx.z, bi = blockIdx.x, bj = blockIdx.y;
    int tx = threadIdx.x & 31, ty = threadIdx.x >> 5;
#pragma unroll
    for (int p = 0; p < 4; p++) {
        int k = bi * 32 + ty + p * 8;
        int r = bj * 32 + tx;
        tile[ty + p * 8][tx] = qkv[(long)(a * 1024 + k) * 3072 + 2048 + r];
    }
    __syncthreads();
#pragma unroll
    for (int p = 0; p < 4; p++) {
        int r = bj * 32 + ty + p * 8;
        int k = bi * 32 + tx;
        Vt[(long)a * 1048576 + (long)r * 1024 + k] = tile[tx][ty + p * 8];
    }
}

// ---------------- bf16 GEMM: C[M][N] = A[M][K] * Bt[N][K]^T (+bias), 1D grid + XCD chunking ----
template<int OUT_BF16>
__global__ __launch_bounds__(256, 2)
void gemm_bt(const short* __restrict__ A, const short* __restrict__ Bt,
             void* __restrict__ Cout, const float* __restrict__ bias,
             int M, int N, int K, int nbx, int cpx) {
    __shared__ short As[2][128 * 32];
    __shared__ short Bs[2][128 * 32];
    const int wg = blockIdx.x;
    const int lg = (wg & 7) * cpx + (wg >> 3);          // bijective: grid % 8 == 0
    const int bx = lg % nbx, by = lg / nbx;
    const int tid = threadIdx.x, w = tid >> 6, lane = tid & 63;
    const int wr = w >> 1, wc = w & 1;
    const int l15 = lane & 15, lhi = lane >> 4;
    const int m0 = by * 128, n0 = bx * 128;
    f32x4 acc[4][4] = {};
    const int NT = K / 32;

    auto stage = [&](int buf, int t) {
        int k0 = t * 32;
#pragma unroll
        for (int j = 0; j < 2; j++) {
            int chunk = w * 128 + j * 64 + lane;
            int row = chunk >> 2, cc = chunk & 3;
            GLOAD_LDS16(A  + (long)(m0 + row) * K + k0 + cc * 8, &As[buf][chunk * 8]);
            GLOAD_LDS16(Bt + (long)(n0 + row) * K + k0 + cc * 8, &Bs[buf][chunk * 8]);
        }
    };

    stage(0, 0);
    __syncthreads();
    int buf = 0;
    for (int t = 0; t < NT; t++) {
        if (t + 1 < NT) stage(buf ^ 1, t + 1);
        short8 af[4], bfr[4];
#pragma unroll
        for (int i = 0; i < 4; i++) {
            af[i]  = *(const short8*)(&As[buf][(wr * 64 + i * 16 + l15) * 32 + lhi * 8]);
            bfr[i] = *(const short8*)(&Bs[buf][(wc * 64 + i * 16 + l15) * 32 + lhi * 8]);
        }
#pragma unroll
        for (int i = 0; i < 4; i++)
#pragma unroll
            for (int j = 0; j < 4; j++)
                acc[i][j] = __builtin_amdgcn_mfma_f32_16x16x32_bf16(af[i], bfr[j], acc[i][j], 0, 0, 0);
        __syncthreads();
        buf ^= 1;
    }
#pragma unroll
    for (int i = 0; i < 4; i++)
#pragma unroll
        for (int j = 0; j < 4; j++)
#pragma unroll
            for (int r = 0; r < 4; r++) {
                int row = m0 + wr * 64 + i * 16 + lhi * 4 + r;
                int col = n0 + wc * 64 + j * 16 + l15;
                float v = acc[i][j][r];
                if (OUT_BF16) ((short*)Cout)[(long)row * N + col] = bf16r(v);
                else          ((float*)Cout)[(long)row * N + col] = v + bias[col];
            }
}

// ---------------- Phase A: Dinv fragment-major, swapped orientation ----------------
// Dinv_f[a][q16][k16][lane][r] holds 1/D at (q=q16*16+(lane&15), k=k16*16+(lane>>4)*4+r)
__global__ __launch_bounds__(256, 2)
void dsum_kernel(const short* __restrict__ qkv, short* __restrict__ Dinv) {
    __shared__ short Qs[2][128 * 64];
    __shared__ short Ks[2][128 * 64];
    const int wg = blockIdx.x;
    const int lg = (wg & 7) * 64 + (wg >> 3);           // 512 blocks, a-chunked per XCD
    const int a = lg >> 6, q0 = ((lg >> 3) & 7) * 128, k0 = (lg & 7) * 128;
    const int tid = threadIdx.x, w = tid >> 6, lane = tid & 63;
    const int wr = w >> 1, wc = w & 1;                  // wr: k-half, wc: q-half
    const int l15 = lane & 15, lhi = lane >> 4;
    const long qb = (long)a * 1024 * 3072;
    f32x4 dacc[4][4] = {};

    auto stage = [&](int buf, int h) {
#pragma unroll
        for (int j = 0; j < 4; j++) {
            int c = (w * 4 + j) * 64 + lane;
            int row = c >> 3, cc = (c & 7) ^ (row & 7);
            GLOAD_LDS16(qkv + qb + (long)(q0 + row) * 3072 + h * 64 + cc * 8,        &Qs[buf][c * 8]);
            GLOAD_LDS16(qkv + qb + (long)(k0 + row) * 3072 + 1024 + h * 64 + cc * 8, &Ks[buf][c * 8]);
        }
    };

    stage(0, 0);
    __syncthreads();
    int buf = 0;
    for (int h = 0; h < 16; h++) {
        if (h < 15) stage(buf ^ 1, h + 1);
        short8 kaf[4][2], qbf[4][2];
#pragma unroll
        for (int i = 0; i < 4; i++) {
            int row = wr * 64 + i * 16 + l15;
#pragma unroll
            for (int df = 0; df < 2; df++)
                kaf[i][df] = *(const short8*)(&Ks[buf][row * 64 + (((df * 4 + lhi) ^ (row & 7)) * 8)]);
        }
#pragma unroll
        for (int j = 0; j < 4; j++) {
            int row = wc * 64 + j * 16 + l15;
#pragma unroll
            for (int df = 0; df < 2; df++)
                qbf[j][df] = *(const short8*)(&Qs[buf][row * 64 + (((df * 4 + lhi) ^ (row & 7)) * 8)]);
        }
#pragma unroll
        for (int i = 0; i < 4; i++)
#pragma unroll
            for (int j = 0; j < 4; j++) {
                f32x4 s = {};
                s = __builtin_amdgcn_mfma_f32_16x16x32_bf16(kaf[i][0], qbf[j][0], s, 0, 0, 0);
                s = __builtin_amdgcn_mfma_f32_16x16x32_bf16(kaf[i][1], qbf[j][1], s, 0, 0, 0);
#pragma unroll
                for (int r = 0; r < 4; r++)
                    dacc[i][j][r] += exp2f(s[r] * SC_LOG2E);
            }
        __syncthreads();
        buf ^= 1;
    }
    // epilogue: lane holds (k = k0+wr*64+i*16+lhi*4+r, q = q0+wc*64+j*16+l15) -> b64 per frag
#pragma unroll
    for (int i = 0; i < 4; i++)
#pragma unroll
        for (int j = 0; j < 4; j++) {
            int q16 = (q0 >> 4) + wc * 4 + j;
            int k16 = (k0 >> 4) + wr * 4 + i;
            short4v s4;
#pragma unroll
            for (int r = 0; r < 4; r++) s4[r] = bf16r(1.0f / dacc[i][j][r]);
            *(short4v*)(Dinv + ((((long)a * 64 + q16) * 64 + k16) << 8) + lane * 4) = s4;
        }
}

// ---------------- Phase B: per-(a,h) attention, swapped QK^T + packed P path ----------------
// 1D grid 1024 (XCD-chunked), 256 thr = 4 waves; wave owns 32 q x 64 d, k in tiles of 64
__global__ __launch_bounds__(256, 2)
void attn2_kernel(const short* __restrict__ qkv, const short* __restrict__ Vt,
                  const short* __restrict__ Dinv, short* __restrict__ ctx) {
    __shared__ short Ks[2][64 * 64];
    __shared__ short Vs[2][64 * 64];
    __shared__ short pbu[4 * 2048];                    // per-wave P[32 q][64 k], chunk-XOR swizzled
    const int wg = blockIdx.x;
    const int lg = (wg & 7) * 128 + (wg >> 3);         // all of one 'a' per XCD
    const int a = lg >> 7, h = (lg >> 3) & 15, q0 = (lg & 7) * 128;
    const int tid = threadIdx.x, w = tid >> 6, lane = tid & 63;
    const int l15 = lane & 15, lhi = lane >> 4;
    const int qw = q0 + w * 32, qw16 = qw >> 4;
    const long qb = (long)a * 1024 * 3072;

    short8 qf[2][2];
#pragma unroll
    for (int qi = 0; qi < 2; qi++)
#pragma unroll
        for (int df = 0; df < 2; df++)
            qf[qi][df] = *(const short8*)(qkv + qb + (long)(qw + qi * 16 + l15) * 3072 + h * 64 + df * 32 + lhi * 8);

    f32x4 oacc[2][4] = {};
    short* pw = &pbu[w * 2048];
    const int sw = (l15 & 7) << 1;                     // even XOR keeps b128 pairs adjacent

    auto stage = [&](int buf, int t) {
        int k0 = t * 64;
#pragma unroll
        for (int j = 0; j < 2; j++) {
            int c = (w * 2 + j) * 64 + lane;
            int row = c >> 3, cc = (c & 7) ^ (row & 7);
            GLOAD_LDS16(qkv + qb + (long)(k0 + row) * 3072 + 1024 + h * 64 + cc * 8, &Ks[buf][c * 8]);
            GLOAD_LDS16(Vt + (long)a * 1048576 + (long)(h * 64 + row) * 1024 + k0 + cc * 8, &Vs[buf][c * 8]);
        }
    };

    stage(0, 0);
    __syncthreads();
    int buf = 0;
    for (int t = 0; t < 16; t++) {
        // Dinv fragment loads: 8 x 8B, lane-indexed (fully coalesced)
        short4v dv4[2][4];
#pragma unroll
        for (int qi = 0; qi < 2; qi++)
#pragma unroll
            for (int kj = 0; kj < 4; kj++)
                dv4[qi][kj] = *(const short4v*)(Dinv + ((((long)a * 64 + qw16 + qi) * 64 + t * 4 + kj) << 8) + lane * 4);
        if (t < 15) stage(buf ^ 1, t + 1);
        // swapped QK^T: C[m=k][n=q] -> lane holds (q=l15, k=kj*16+lhi*4+r)
        f32x4 sacc[2][4] = {};
#pragma unroll
        for (int kj = 0; kj < 4; kj++) {
            int row = kj * 16 + l15;
#pragma unroll
            for (int df = 0; df < 2; df++) {
                short8 kf = *(const short8*)(&Ks[buf][row * 64 + (((df * 4 + lhi) ^ (row & 7)) * 8)]);
#pragma unroll
                for (int qi = 0; qi < 2; qi++)
                    sacc[qi][kj] = __builtin_amdgcn_mfma_f32_16x16x32_bf16(kf, qf[qi][df], sacc[qi][kj], 0, 0, 0);
            }
        }
        // P = exp2(s*c)*Dinv -> pb[q][k], 4 consecutive k per lane = one b64 write
#pragma unroll
        for (int qi = 0; qi < 2; qi++) {
            int q = qi * 16 + l15;
#pragma unroll
            for (int kj = 0; kj < 4; kj++) {
                short4v s4;
#pragma unroll
                for (int r = 0; r < 4; r++)
                    s4[r] = bf16r(exp2f(sacc[qi][kj][r] * SC_LOG2E) * bf2f((unsigned short)dv4[qi][kj][r]));
                int cc = (kj * 4 + lhi) ^ sw;
                *(short4v*)(&pw[q * 64 + cc * 4]) = s4;
            }
        }
        // PV: A = P[q][k] (b128 reads), B = Vs rows (d-major)
#pragma unroll
        for (int qi = 0; qi < 2; qi++) {
            int q = qi * 16 + l15;
            short8 pf[2];
#pragma unroll
            for (int kc = 0; kc < 2; kc++) {
                int cc = (kc * 8 + lhi * 2) ^ sw;
                pf[kc] = *(const short8*)(&pw[q * 64 + cc * 4]);
            }
#pragma unroll
            for (int dj = 0; dj < 4; dj++) {
                int vrow = dj * 16 + l15;
#pragma unroll
                for (int kc = 0; kc < 2; kc++) {
                    short8 vf = *(const short8*)(&Vs[buf][vrow * 64 + (((kc * 4 + lhi) ^ (vrow & 7)) * 8)]);
                    oacc[qi][dj] = __builtin_amdgcn_mfma_f32_16x16x32_bf16(pf[kc], vf, oacc[qi][dj], 0, 0, 0);
                }
            }
        }
        __syncthreads();
        buf ^= 1;
    }
#pragma unroll
    for (int qi = 0; qi < 2; qi++)
#pragma unroll
        for (int dj = 0; dj < 4; dj++)
#pragma unroll
            for (int r = 0; r < 4; r++) {
                int q = qw + qi * 16 + lhi * 4 + r;
                ctx[((long)a * 1024 + q) * 1024 + h * 64 + dj * 16 + l15] = bf16r(oacc[qi][dj][r]);
            }
}

extern "C" void kernel_launch(void* const* d_in, const int* in_sizes, int n_in,
                              void* d_out, int out_size, void* d_ws, size_t ws_size,
                              hipStream_t stream) {
    const float* x     = (const float*)d_in[0];
    const float* w_qkv = (const float*)d_in[1];
    const float* w_out = (const float*)d_in[2];
    const float* b_out = (const float*)d_in[3];
    float* out = (float*)d_out;

    char* ws = (char*)d_ws;
    short* xb    = (short*)(ws);               // 16 MB  x bf16 (dead after gemm1)
    short* Dinv  = (short*)(ws);               // 16 MB  Dinv fragment-major (reuses xb slot)
    short* wqkvT = (short*)(ws + 16777216);    //  6 MB  w_qkv^T bf16 [3072][1024]
    short* woT   = (short*)(ws + 23068672);    //  2 MB  w_out^T bf16 [1024][1024]
    short* qkv   = (short*)(ws + 25165824);    // 48 MB  qkv bf16 [8192][3072]
    short* Vt    = (short*)(ws + 75497472);    // 16 MB  V^T bf16 [8][1024][1024]
    short* ctx   = (short*)(ws + 92274688);    // 16 MB  attn out bf16 [8192][1024]
    if (ws_size < 109051904u) return;

    castk<<<8192, 256, 0, stream>>>(x, xb, 2097152);
    tcast<<<dim3(32, 96), 256, 0, stream>>>(w_qkv, wqkvT, 1024, 3072);
    tcast<<<dim3(32, 32), 256, 0, stream>>>(w_out, woT, 1024, 1024);
    gemm_bt<1><<<1536, 256, 0, stream>>>(xb, wqkvT, (void*)qkv, nullptr, 8192, 3072, 1024, 24, 192);
    vtrans<<<dim3(32, 32, 8), 256, 0, stream>>>(qkv, Vt);
    dsum_kernel<<<512, 256, 0, stream>>>(qkv, Dinv);
    attn2_kernel<<<1024, 256, 0, stream>>>(qkv, Vt, Dinv, ctx);
    gemm_bt<0><<<512, 256, 0, stream>>>(ctx, woT, (void*)out, b_out, 8192, 1024, 1024, 8, 64);
}

// Round 4
// 228.111 us; speedup vs baseline: 1.5423x; 1.0377x over previous
//
#include <hip/hip_runtime.h>
#include <hip/hip_bf16.h>

typedef __attribute__((ext_vector_type(8))) short short8;
typedef __attribute__((ext_vector_type(4))) short short4v;
typedef __attribute__((ext_vector_type(4))) float f32x4;
typedef __attribute__((ext_vector_type(16))) float f32x16;
typedef __attribute__((ext_vector_type(4))) unsigned uint4v;

#define SC_LOG2E 0.04508422f   // (1/32) * log2(e)
#define MFMA32(a, b, c) __builtin_amdgcn_mfma_f32_32x32x16_bf16(a, b, c, 0, 0, 0)

__device__ inline short bf16r(float f) {
    union { float f; unsigned u; } v; v.f = f;
    unsigned r = v.u + 0x7FFFu + ((v.u >> 16) & 1u);
    return (short)(r >> 16);
}
__device__ inline float bflo(unsigned u) {
    union { unsigned u; float f; } v; v.u = u << 16; return v.f;
}
__device__ inline float bfhi(unsigned u) {
    union { unsigned u; float f; } v; v.u = u & 0xffff0000u; return v.f;
}
__device__ inline unsigned cvt_pk_bf16(float lo, float hi) {
    unsigned r;
    asm("v_cvt_pk_bf16_f32 %0, %1, %2" : "=v"(r) : "v"(lo), "v"(hi));
    return r;
}
// exchanges a.hi(lanes32-63) <-> b.lo(lanes0-31): a'=[a.lo,b.lo], b'=[a.hi,b.hi]
__device__ inline void perm32swap(unsigned& a, unsigned& b) {
    asm("v_permlane32_swap_b32 %0, %1" : "+v"(a), "+v"(b));
}

#define GLOAD_LDS16(gp, lp) __builtin_amdgcn_global_load_lds( \
    (const __attribute__((address_space(1))) unsigned int*)(gp), \
    (__attribute__((address_space(3))) unsigned int*)(lp), 16, 0, 0)

// ---------------- elementwise cast fp32 -> bf16 ----------------
__global__ void castk(const float* __restrict__ in, short* __restrict__ out, int n4) {
    int i = blockIdx.x * 256 + threadIdx.x;
    if (i < n4) {
        float4 v = ((const float4*)in)[i];
        short4 o;
        o.x = bf16r(v.x); o.y = bf16r(v.y); o.z = bf16r(v.z); o.w = bf16r(v.w);
        ((short4*)out)[i] = o;
    }
}

// ---------------- transpose-cast fp32[R][C] -> bf16[C][R] ----------------
__global__ void tcast(const float* __restrict__ src, short* __restrict__ dst, int R, int C) {
    __shared__ float tile[32][33];
    int bi = blockIdx.x, bj = blockIdx.y;
    int tx = threadIdx.x & 31, ty = threadIdx.x >> 5;
#pragma unroll
    for (int p = 0; p < 4; p++)
        tile[ty + p * 8][tx] = src[(long)(bi * 32 + ty + p * 8) * C + bj * 32 + tx];
    __syncthreads();
#pragma unroll
    for (int p = 0; p < 4; p++)
        dst[(long)(bj * 32 + ty + p * 8) * R + bi * 32 + tx] = bf16r(tile[tx][ty + p * 8]);
}

// ---------------- transpose V slice of qkv (bf16) -> Vt[a][r=h*64+d][k] ----------------
__global__ void vtrans(const short* __restrict__ qkv, short* __restrict__ Vt) {
    __shared__ short tile[32][33];
    int a = blockIdx.z, bi = blockIdx.x, bj = blockIdx.y;
    int tx = threadIdx.x & 31, ty = threadIdx.x >> 5;
#pragma unroll
    for (int p = 0; p < 4; p++) {
        int k = bi * 32 + ty + p * 8;
        int r = bj * 32 + tx;
        tile[ty + p * 8][tx] = qkv[(long)(a * 1024 + k) * 3072 + 2048 + r];
    }
    __syncthreads();
#pragma unroll
    for (int p = 0; p < 4; p++) {
        int r = bj * 32 + ty + p * 8;
        int k = bi * 32 + tx;
        Vt[(long)a * 1048576 + (long)r * 1024 + k] = tile[tx][ty + p * 8];
    }
}

// ---------------- bf16 GEMM: C[M][N] = A[M][K] * Bt[N][K]^T (+bias), 1D grid + XCD chunking ----
template<int OUT_BF16>
__global__ __launch_bounds__(256, 2)
void gemm_bt(const short* __restrict__ A, const short* __restrict__ Bt,
             void* __restrict__ Cout, const float* __restrict__ bias,
             int M, int N, int K, int nbx, int cpx) {
    __shared__ short As[2][128 * 32];
    __shared__ short Bs[2][128 * 32];
    const int wg = blockIdx.x;
    const int lg = (wg & 7) * cpx + (wg >> 3);
    const int bx = lg % nbx, by = lg / nbx;
    const int tid = threadIdx.x, w = tid >> 6, lane = tid & 63;
    const int wr = w >> 1, wc = w & 1;
    const int l15 = lane & 15, lhi = lane >> 4;
    const int m0 = by * 128, n0 = bx * 128;
    f32x4 acc[4][4] = {};
    const int NT = K / 32;

    auto stage = [&](int buf, int t) {
        int k0 = t * 32;
#pragma unroll
        for (int j = 0; j < 2; j++) {
            int chunk = w * 128 + j * 64 + lane;
            int row = chunk >> 2, cc = chunk & 3;
            GLOAD_LDS16(A  + (long)(m0 + row) * K + k0 + cc * 8, &As[buf][chunk * 8]);
            GLOAD_LDS16(Bt + (long)(n0 + row) * K + k0 + cc * 8, &Bs[buf][chunk * 8]);
        }
    };

    stage(0, 0);
    __syncthreads();
    int buf = 0;
    for (int t = 0; t < NT; t++) {
        if (t + 1 < NT) stage(buf ^ 1, t + 1);
        short8 af[4], bfr[4];
#pragma unroll
        for (int i = 0; i < 4; i++) {
            af[i]  = *(const short8*)(&As[buf][(wr * 64 + i * 16 + l15) * 32 + lhi * 8]);
            bfr[i] = *(const short8*)(&Bs[buf][(wc * 64 + i * 16 + l15) * 32 + lhi * 8]);
        }
#pragma unroll
        for (int i = 0; i < 4; i++)
#pragma unroll
            for (int j = 0; j < 4; j++)
                acc[i][j] = __builtin_amdgcn_mfma_f32_16x16x32_bf16(af[i], bfr[j], acc[i][j], 0, 0, 0);
        __syncthreads();
        buf ^= 1;
    }
#pragma unroll
    for (int i = 0; i < 4; i++)
#pragma unroll
        for (int j = 0; j < 4; j++)
#pragma unroll
            for (int r = 0; r < 4; r++) {
                int row = m0 + wr * 64 + i * 16 + lhi * 4 + r;
                int col = n0 + wc * 64 + j * 16 + l15;
                float v = acc[i][j][r];
                if (OUT_BF16) ((short*)Cout)[(long)row * N + col] = bf16r(v);
                else          ((float*)Cout)[(long)row * N + col] = v + bias[col];
            }
}

// ---------------- Phase A: Dinv, swapped 32x32, packed-bf16 fragment-major output -------
// Dinv layout: [a][k32 0..31][q32 0..31][lane 0..63][8 u32]; word w = (reg 2w | reg 2w+1 <<16)
// where (k = k32*32 + (r&3)+8*(r>>2)+4*(lane>>5), q = q32*32 + (lane&31))
__global__ __launch_bounds__(256, 2)
void dsum_kernel(const short* __restrict__ qkv, unsigned* __restrict__ Dinv) {
    __shared__ short Qs[2][128 * 64];
    __shared__ short Ks[2][128 * 64];
    const int wg = blockIdx.x;
    const int lg = (wg & 7) * 64 + (wg >> 3);
    const int a = lg >> 6, q0 = ((lg >> 3) & 7) * 128, k0 = (lg & 7) * 128;
    const int tid = threadIdx.x, w = tid >> 6, lane = tid & 63;
    const int wr = w >> 1, wc = w & 1;                 // wr: k-half, wc: q-half
    const int l31 = lane & 31, hi = lane >> 5;
    const long qb = (long)a * 3145728;
    f32x16 dacc[2][2] = {};

    auto stage = [&](int buf, int hh) {
#pragma unroll
        for (int j = 0; j < 4; j++) {
            int c = j * 256 + tid;
            int row = c >> 3, cc = (c & 7) ^ (row & 7);
            GLOAD_LDS16(qkv + qb + (long)(q0 + row) * 3072 + hh * 64 + cc * 8,        &Qs[buf][c * 8]);
            GLOAD_LDS16(qkv + qb + (long)(k0 + row) * 3072 + 1024 + hh * 64 + cc * 8, &Ks[buf][c * 8]);
        }
    };

    stage(0, 0);
    __syncthreads();
    int buf = 0;
    for (int hh = 0; hh < 16; hh++) {
        if (hh < 15) stage(buf ^ 1, hh + 1);
        short8 ka[2][4], qf[2][4];
#pragma unroll
        for (int i = 0; i < 2; i++)
#pragma unroll
            for (int dc = 0; dc < 4; dc++) {
                int row = wr * 64 + i * 32 + l31;
                int ph = (dc * 2 + hi) ^ (row & 7);
                ka[i][dc] = *(const short8*)(&Ks[buf][row * 64 + ph * 8]);
            }
#pragma unroll
        for (int j = 0; j < 2; j++)
#pragma unroll
            for (int dc = 0; dc < 4; dc++) {
                int row = wc * 64 + j * 32 + l31;
                int ph = (dc * 2 + hi) ^ (row & 7);
                qf[j][dc] = *(const short8*)(&Qs[buf][row * 64 + ph * 8]);
            }
#pragma unroll
        for (int i = 0; i < 2; i++)
#pragma unroll
            for (int j = 0; j < 2; j++) {
                f32x16 s = {};
#pragma unroll
                for (int dc = 0; dc < 4; dc++)
                    s = MFMA32(ka[i][dc], qf[j][dc], s);
#pragma unroll
                for (int r = 0; r < 16; r++)
                    dacc[i][j][r] += exp2f(s[r] * SC_LOG2E);
            }
        __syncthreads();
        buf ^= 1;
    }
#pragma unroll
    for (int i = 0; i < 2; i++)
#pragma unroll
        for (int j = 0; j < 2; j++) {
            int ktg = (k0 >> 5) + wr * 2 + i;
            int qtg = (q0 >> 5) + wc * 2 + j;
            unsigned pw[8];
#pragma unroll
            for (int u = 0; u < 8; u++)
                pw[u] = cvt_pk_bf16(1.0f / dacc[i][j][2 * u], 1.0f / dacc[i][j][2 * u + 1]);
            unsigned* dst = Dinv + (((long)a * 32 + ktg) * 32 + qtg) * 512 + lane * 8;
            *(uint4v*)dst       = (uint4v){pw[0], pw[1], pw[2], pw[3]};
            *(uint4v*)(dst + 4) = (uint4v){pw[4], pw[5], pw[6], pw[7]};
        }
}

// ---------------- Phase B: per-(a,h) attention, 32x32 frags, in-register P ----------------
// grid 512 (XCD-chunked by a), 256 thr = 4 waves; wave owns 64 q, k-tiles of 64
__global__ __launch_bounds__(256, 2)
void attn2_kernel(const short* __restrict__ qkv, const short* __restrict__ Vt,
                  const unsigned* __restrict__ Dinv, short* __restrict__ ctx) {
    __shared__ short Ks[2][64 * 64];
    __shared__ short Vs[2][64 * 64];
    const int wg = blockIdx.x;
    const int lg = (wg & 7) * 64 + (wg >> 3);
    const int a = lg >> 6, h = (lg >> 2) & 15, qblk = lg & 3;
    const int q0 = qblk * 256;
    const int tid = threadIdx.x, w = tid >> 6, lane = tid & 63;
    const int l31 = lane & 31, hi = lane >> 5;
    const int qw = q0 + w * 64;
    const long qb = (long)a * 3145728;

    // Q fragments (B-operand): lane holds Q[q = qw+qs*32+l31][d = dc*16 + hi*8 + j]
    short8 qfrag[2][4];
#pragma unroll
    for (int qs = 0; qs < 2; qs++)
#pragma unroll
        for (int dc = 0; dc < 4; dc++)
            qfrag[qs][dc] = *(const short8*)(qkv + qb +
                (long)(qw + qs * 32 + l31) * 3072 + h * 64 + dc * 16 + hi * 8);

    f32x16 oacc[2][2] = {};   // [qs][dt]

    auto stage = [&](int buf, int t) {
#pragma unroll
        for (int j = 0; j < 2; j++) {
            int c = j * 256 + tid;
            int row = c >> 3, cc = (c & 7) ^ (row & 7);
            GLOAD_LDS16(qkv + qb + (long)(a * 0 + t * 64 + row) * 3072 + (long)a * 0 +
                        (long)(0) + 1024 + h * 64 + cc * 8 + (long)(t * 0), &Ks[buf][c * 8]);
            GLOAD_LDS16(Vt + (long)a * 1048576 + (long)(h * 64 + row) * 1024 + t * 64 + cc * 8,
                        &Vs[buf][c * 8]);
        }
    };
    // NOTE: K row global index is a*1024 + t*64 + row; fold a into base pointer:
    const short* kbase = qkv + qb + 1024 + h * 64;

    // re-define staging with clean addressing
    auto stage2 = [&](int buf, int t) {
#pragma unroll
        for (int j = 0; j < 2; j++) {
            int c = j * 256 + tid;
            int row = c >> 3, cc = (c & 7) ^ (row & 7);
            GLOAD_LDS16(kbase + (long)(t * 64 + row) * 3072 + cc * 8, &Ks[buf][c * 8]);
            GLOAD_LDS16(Vt + (long)a * 1048576 + (long)(h * 64 + row) * 1024 + t * 64 + cc * 8,
                        &Vs[buf][c * 8]);
        }
    };
    (void)stage;

    const unsigned* dbase = Dinv + ((long)a * 1024) * 512 + lane * 8;  // + (kt_g*32 + qt_g)*512

    stage2(0, 0);
    __syncthreads();
    int buf = 0;
    for (int t = 0; t < 16; t++) {
        // Dinv prefetch: [qs][kt][half]
        uint4v dv[2][2][2];
#pragma unroll
        for (int qs = 0; qs < 2; qs++)
#pragma unroll
            for (int kt = 0; kt < 2; kt++) {
                int qtg = qblk * 8 + w * 2 + qs;
                int ktg = t * 2 + kt;
                const unsigned* dp = dbase + ((long)ktg * 32 + qtg) * 512;
                dv[qs][kt][0] = *(const uint4v*)dp;
                dv[qs][kt][1] = *(const uint4v*)(dp + 4);
            }
        if (t < 15) stage2(buf ^ 1, t + 1);

        short8 pfrag[2][4];   // [qs][n = kt*2 + k16half]
#pragma unroll
        for (int kt = 0; kt < 2; kt++) {
            short8 ka[4];
#pragma unroll
            for (int dc = 0; dc < 4; dc++) {
                int row = kt * 32 + l31;
                int ph = (dc * 2 + hi) ^ (row & 7);
                ka[dc] = *(const short8*)(&Ks[buf][row * 64 + ph * 8]);
            }
#pragma unroll
            for (int qs = 0; qs < 2; qs++) {
                f32x16 s = {};
#pragma unroll
                for (int dc = 0; dc < 4; dc++)
                    s = MFMA32(ka[dc], qfrag[qs][dc], s);
                // P = exp2(s*c) * Dinv, packed to bf16 pairs
                unsigned pw[8];
#pragma unroll
                for (int u = 0; u < 8; u++) {
                    unsigned dm = dv[qs][kt][u >> 2][u & 3];
                    float e0 = exp2f(s[2 * u]     * SC_LOG2E) * bflo(dm);
                    float e1 = exp2f(s[2 * u + 1] * SC_LOG2E) * bfhi(dm);
                    pw[u] = cvt_pk_bf16(e0, e1);
                }
                // in-register transpose to A-fragment layout (T12): one swap fills two words
                perm32swap(pw[0], pw[2]); perm32swap(pw[1], pw[3]);
                perm32swap(pw[4], pw[6]); perm32swap(pw[5], pw[7]);
                union { uint4v u; short8 s8; } c0, c1;
                c0.u = (uint4v){pw[0], pw[1], pw[2], pw[3]};
                c1.u = (uint4v){pw[4], pw[5], pw[6], pw[7]};
                pfrag[qs][kt * 2 + 0] = c0.s8;
                pfrag[qs][kt * 2 + 1] = c1.s8;
            }
        }
        // PV: oacc[qs][dt] += P * V   (A = P frags, B = Vt rows)
#pragma unroll
        for (int dt = 0; dt < 2; dt++)
#pragma unroll
            for (int n = 0; n < 4; n++) {
                int row = dt * 32 + l31;
                int ph = (n * 2 + hi) ^ (row & 7);
                short8 vf = *(const short8*)(&Vs[buf][row * 64 + ph * 8]);
#pragma unroll
                for (int qs = 0; qs < 2; qs++)
                    oacc[qs][dt] = MFMA32(pfrag[qs][n], vf, oacc[qs][dt]);
            }
        __syncthreads();
        buf ^= 1;
    }
    // epilogue: ctx[a*1024+q][h*64 + dt*32 + l31]
#pragma unroll
    for (int qs = 0; qs < 2; qs++)
#pragma unroll
        for (int dt = 0; dt < 2; dt++)
#pragma unroll
            for (int r = 0; r < 16; r++) {
                int q = qw + qs * 32 + (r & 3) + 8 * (r >> 2) + 4 * hi;
                int col = h * 64 + dt * 32 + l31;
                ctx[((long)a * 1024 + q) * 1024 + col] = bf16r(oacc[qs][dt][r]);
            }
}

extern "C" void kernel_launch(void* const* d_in, const int* in_sizes, int n_in,
                              void* d_out, int out_size, void* d_ws, size_t ws_size,
                              hipStream_t stream) {
    const float* x     = (const float*)d_in[0];
    const float* w_qkv = (const float*)d_in[1];
    const float* w_out = (const float*)d_in[2];
    const float* b_out = (const float*)d_in[3];
    float* out = (float*)d_out;

    char* ws = (char*)d_ws;
    short* xb       = (short*)(ws);               // 16 MB  x bf16 (dead after gemm1)
    unsigned* Dinv  = (unsigned*)(ws);            // 16 MB  Dinv packed frag-major (reuses xb)
    short* wqkvT = (short*)(ws + 16777216);       //  6 MB  w_qkv^T bf16 [3072][1024]
    short* woT   = (short*)(ws + 23068672);       //  2 MB  w_out^T bf16 [1024][1024]
    short* qkv   = (short*)(ws + 25165824);       // 48 MB  qkv bf16 [8192][3072]
    short* Vt    = (short*)(ws + 75497472);       // 16 MB  V^T bf16 [8][1024][1024]
    short* ctx   = (short*)(ws + 92274688);       // 16 MB  attn out bf16 [8192][1024]
    if (ws_size < 109051904u) return;

    castk<<<8192, 256, 0, stream>>>(x, xb, 2097152);
    tcast<<<dim3(32, 96), 256, 0, stream>>>(w_qkv, wqkvT, 1024, 3072);
    tcast<<<dim3(32, 32), 256, 0, stream>>>(w_out, woT, 1024, 1024);
    gemm_bt<1><<<1536, 256, 0, stream>>>(xb, wqkvT, (void*)qkv, nullptr, 8192, 3072, 1024, 24, 192);
    vtrans<<<dim3(32, 32, 8), 256, 0, stream>>>(qkv, Vt);
    dsum_kernel<<<512, 256, 0, stream>>>(qkv, Dinv);
    attn2_kernel<<<512, 256, 0, stream>>>(qkv, Vt, Dinv, ctx);
    gemm_bt<0><<<512, 256, 0, stream>>>(ctx, woT, (void*)out, b_out, 8192, 1024, 1024, 8, 64);
}